// Round 6
// baseline (395.060 us; speedup 1.0000x reference)
//
#include <hip/hip_runtime.h>
#include <hip/hip_bf16.h>

#define N_TOK 2048
#define HID   2048
#define NH    32
#define NKV   8
#define HD    64
#define NEXP  4
#define CHUNK (N_TOK / NEXP)   // 512

typedef __attribute__((ext_vector_type(8))) short short8;
typedef __attribute__((ext_vector_type(4))) short short4v;
typedef __attribute__((ext_vector_type(4))) float float4v;

#define QSCALE (0.125f * 1.44269504f)   // softmax scale * log2e (exp2 domain)
#define RLOG   0.41524101186f           // log2(1e4)/32

__device__ inline short f2bf(float f) {
    __hip_bfloat16 h = __float2bfloat16(f);
    return *reinterpret_cast<short*>(&h);
}
__device__ inline float bf2f(short s) {
    __hip_bfloat16 h = *reinterpret_cast<__hip_bfloat16*>(&s);
    return __bfloat162float(h);
}
__device__ __forceinline__ float fast_exp2(float x) {
    float r;
    asm("v_exp_f32 %0, %1" : "=v"(r) : "v"(x));
    return r;
}

// async global->LDS, 16 B per lane; wave-uniform LDS base (m104 caveat).
__device__ __forceinline__ void gld_lds16(const void* g, void* l) {
    __builtin_amdgcn_global_load_lds(
        (const __attribute__((address_space(1))) unsigned int*)g,
        (__attribute__((address_space(3))) unsigned int*)l, 16, 0, 0);
}

// ---------------------------------------------------------------------------
// wtrans tile body: fp32 [k0+64)x[n0+64) of in (row stride Nw) -> bf16
// out[n][2048] transposed; float4-vectorized load, short8-vectorized store.
// ---------------------------------------------------------------------------
__device__ __forceinline__ void wtrans_tile(
    const float* __restrict__ in, short* __restrict__ out, int Nw,
    int k0, int n0, float (*T)[65], int t)
{
    const int nl4 = (t & 15) * 4;
    const int kl  = t >> 4;
#pragma unroll
    for (int i = 0; i < 4; i++) {
        float4 v = *(const float4*)&in[(size_t)(k0 + kl + i * 16) * Nw + n0 + nl4];
        float* Tr = &T[kl + i * 16][nl4];
        Tr[0] = v.x; Tr[1] = v.y; Tr[2] = v.z; Tr[3] = v.w;
    }
    __syncthreads();
#pragma unroll
    for (int i = 0; i < 2; i++) {
        int idx = t + i * 256;
        int nl = idx >> 3, k8 = (idx & 7) * 8;
        short8 s;
#pragma unroll
        for (int j = 0; j < 8; j++) s[j] = f2bf(T[k8 + j][nl]);
        *(short8*)&out[(size_t)(n0 + nl) * 2048 + k0 + k8] = s;
    }
}

// ---------------------------------------------------------------------------
// prep1: [0,2048) cvt hidden->bf16 | [2048,6144) wtrans q_proj_w |
//        [6144,6656) wtrans k_w/v_w.
// ---------------------------------------------------------------------------
__global__ __launch_bounds__(256)
void prep1(const float* __restrict__ hidden, const float* __restrict__ qw,
           const float* __restrict__ kw, const float* __restrict__ vw,
           short* __restrict__ Xbf, short* __restrict__ Wq,
           short* __restrict__ Wkv)
{
    __shared__ float T[64][65];
    const int b = blockIdx.x;
    const int t = threadIdx.x;

    if (b < 2048) {
        size_t i = (size_t)b * 256 + t;
        float4 a = ((const float4*)hidden)[i * 2];
        float4 c = ((const float4*)hidden)[i * 2 + 1];
        short8 s;
        s[0] = f2bf(a.x); s[1] = f2bf(a.y); s[2] = f2bf(a.z); s[3] = f2bf(a.w);
        s[4] = f2bf(c.x); s[5] = f2bf(c.y); s[6] = f2bf(c.z); s[7] = f2bf(c.w);
        ((short8*)Xbf)[i] = s;
    } else if (b < 6144) {
        int b2 = b - 2048;
        int k0 = (b2 & 31) * 64, n0 = ((b2 >> 5) & 31) * 64, e = b2 >> 10;
        wtrans_tile(qw + (size_t)e * 2048 * 2048, Wq + (size_t)e * 2048 * 2048,
                    2048, k0, n0, T, t);
    } else {
        int b3 = b - 6144;
        int k0 = (b3 & 31) * 64, n0 = ((b3 >> 5) & 7) * 64, z = b3 >> 8;
        wtrans_tile(z ? vw : kw, Wkv + (size_t)z * 512 * 2048, 512, k0, n0, T, t);
    }
}

// ---------------------------------------------------------------------------
// bf16 MFMA GEMM core, 64x128 tile (M x N), BK=32, 4 waves (wave = 32x64).
// R3 config kept: 2-phase vmcnt(0) rhythm, XOR-swizzled k-granules
// (conflicts==0), 768/512-block grids.
// Fused epilogues (wave N-tile 64 cols == one head):
//   EPI 0: fp32 store (o-proj)
//   EPI 1: q RMSNorm + RoPE + QSCALE, bf16 store to qb (stride 2048)
//   EPI 2: kv GEMM -- k cols (n<512): RMSNorm+RoPE -> kb (stride 512);
//          v cols: transposed bf16 store to vt[d][token] (stride 2048)
// ---------------------------------------------------------------------------
template <int EPI>
__device__ __forceinline__ void gemm_core(
    const short* __restrict__ X, const short* __restrict__ Wt,
    const int* __restrict__ sidx, void* __restrict__ OUT,
    int dout, bool routed, int bx, int by,
    const int* __restrict__ positions, const float* __restrict__ nw,
    short* __restrict__ vt,
    short* As0, short* Bs0, short* As1, short* Bs1, int* ridx)
{
    const int t  = threadIdx.x;
    const int m0 = by * 64;
    const int n0 = bx * 128;

    if (t < 64) ridx[t] = routed ? sidx[m0 + t] : (m0 + t);
    __syncthreads();

    const short* Wb = Wt + (routed ? (size_t)(m0 / CHUNK) * (size_t)dout * 2048 : 0);

    // XOR-swizzled k-granule for staging: LDS row r = t>>2 holds global
    // granule (x ^ ((r>>1)&3)) at granule slot x. (r>>1)&3 == (t>>3)&3.
    const int seg = (((t & 3) ^ ((t >> 3) & 3))) * 8;
    const short* ga0 = X  + (size_t)ridx[t >> 2] * 2048 + seg;
    const short* gb0 = Wb + (size_t)(n0 + (t >> 2)) * 2048 + seg;
    const short* gb1 = Wb + (size_t)(n0 + 64 + (t >> 2)) * 2048 + seg;

    const int lane = t & 63;
    const int wave = t >> 6;
    const int wl   = wave * 64 * 8;
    const int col  = lane & 15;
    const int rowg = lane >> 4;
    const int wm   = (wave >> 1) * 32;   // M-half of the 64-row tile
    const int wn   = (wave & 1) * 64;    // N-half (one head)

    // read-side swizzle: granule for tile row R at slot rowg ^ ((R>>1)&3);
    // (R>>1)&3 == (col>>1)&3 since wm, i*16 are 0 mod 8.
    const int swz = (col >> 1) & 3;
    int offA[2], offB[4];
#pragma unroll
    for (int i = 0; i < 2; i++)
        offA[i] = (wm + i * 16 + col) * 32 + ((rowg ^ swz) * 8);
#pragma unroll
    for (int i = 0; i < 4; i++)
        offB[i] = (wn + i * 16 + col) * 32 + ((rowg ^ swz) * 8);

    float4v acc[2][4];
#pragma unroll
    for (int mt = 0; mt < 2; mt++)
#pragma unroll
        for (int nt = 0; nt < 4; nt++) acc[mt][nt] = (float4v){0.f, 0.f, 0.f, 0.f};

    auto stage = [&](int k0, short* A, short* B) {
        gld_lds16(ga0 + k0, A + wl);                 // A: 64 rows, 4 KB
        gld_lds16(gb0 + k0, B + wl);                 // B rows 0-63
        gld_lds16(gb1 + k0, B + 256 * 8 + wl);       // B rows 64-127
    };
    auto compute = [&](const short* A, const short* B) {
        short8 af[2], bfr[4];
#pragma unroll
        for (int i = 0; i < 2; i++) af[i] = *(const short8*)&A[offA[i]];
#pragma unroll
        for (int i = 0; i < 4; i++) bfr[i] = *(const short8*)&B[offB[i]];
#pragma unroll
        for (int mt = 0; mt < 2; mt++)
#pragma unroll
            for (int nt = 0; nt < 4; nt++)
                acc[mt][nt] = __builtin_amdgcn_mfma_f32_16x16x32_bf16(
                    af[mt], bfr[nt], acc[mt][nt], 0, 0, 0);
    };

    stage(0, As0, Bs0);
    asm volatile("s_waitcnt vmcnt(0)" ::: "memory");
    __builtin_amdgcn_s_barrier();

#pragma unroll 1
    for (int k0 = 0; k0 < 2048; k0 += 64) {
        stage(k0 + 32, As1, Bs1);
        compute(As0, Bs0);
        asm volatile("s_waitcnt vmcnt(0)" ::: "memory");
        __builtin_amdgcn_s_barrier();

        if (k0 + 64 < 2048) stage(k0 + 64, As0, Bs0);
        compute(As1, Bs1);
        asm volatile("s_waitcnt vmcnt(0)" ::: "memory");
        __builtin_amdgcn_s_barrier();
    }

    if (EPI == 0) {
#pragma unroll
        for (int mt = 0; mt < 2; mt++)
#pragma unroll
            for (int r = 0; r < 4; r++) {
                int row = ridx[wm + mt * 16 + rowg * 4 + r];
#pragma unroll
                for (int nt = 0; nt < 4; nt++)
                    ((float*)OUT)[(size_t)row * dout + n0 + wn + nt * 16 + col] =
                        acc[mt][nt][r];
            }
        return;
    }

    const bool is_v = (EPI == 2) && (n0 + wn >= 512);

    if (is_v) {   // transposed bf16 store: vt[d][token], 4 tokens per store
#pragma unroll
        for (int mt = 0; mt < 2; mt++) {
            int rowb = m0 + wm + mt * 16 + rowg * 4;   // identity rows (kv)
#pragma unroll
            for (int nt = 0; nt < 4; nt++) {
                int d = n0 + wn + nt * 16 + col - 512;
                short4v sv;
#pragma unroll
                for (int r = 0; r < 4; r++) sv[r] = f2bf(acc[mt][nt][r]);
                *(short4v*)&vt[(size_t)d * N_TOK + rowb] = sv;
            }
        }
        return;
    }

    // q (EPI 1) or k (EPI 2, n<512): RMSNorm + NeoX RoPE, bf16 store
    {
        const int   h     = (n0 + wn) >> 6;
        const float oscl  = (EPI == 1) ? QSCALE : 1.0f;
        const int   ldo   = (EPI == 1) ? 2048 : 512;
        short* ob = (short*)OUT;
        float invf0 = fast_exp2(-(float)col * RLOG);          // j = col
        float invf1 = fast_exp2(-(float)(16 + col) * RLOG);   // j = 16+col
        float wv[4];
#pragma unroll
        for (int nt = 0; nt < 4; nt++) wv[nt] = nw[nt * 16 + col];

#pragma unroll
        for (int mt = 0; mt < 2; mt++)
#pragma unroll
            for (int r = 0; r < 4; r++) {
                int row = ridx[wm + mt * 16 + rowg * 4 + r];
                float x0 = acc[mt][0][r], x1 = acc[mt][1][r];
                float x2 = acc[mt][2][r], x3 = acc[mt][3][r];
                float ss = x0 * x0 + x1 * x1 + x2 * x2 + x3 * x3;
#pragma unroll
                for (int off = 1; off < 16; off <<= 1)
                    ss += __shfl_xor(ss, off, 64);
                float rs = rsqrtf(ss * (1.0f / HD) + 1e-6f);
                x0 *= rs * wv[0]; x1 *= rs * wv[1];
                x2 *= rs * wv[2]; x3 *= rs * wv[3];
                float pos = (float)positions[row];
                float fr0 = pos * invf0, fr1 = pos * invf1;
                float c0 = __cosf(fr0), s0 = __sinf(fr0);
                float c1 = __cosf(fr1), s1 = __sinf(fr1);
                float o0 = x0 * c0 - x2 * s0;
                float o1 = x1 * c1 - x3 * s1;
                float o2 = x2 * c0 + x0 * s0;
                float o3 = x3 * c1 + x1 * s1;
                size_t base = (size_t)row * ldo + h * 64 + col;
                ob[base]      = f2bf(o0 * oscl);
                ob[base + 16] = f2bf(o1 * oscl);
                ob[base + 32] = f2bf(o2 * oscl);
                ob[base + 48] = f2bf(o3 * oscl);
            }
    }
}

// fused q-proj (512 blocks, routed, EPI1) + kv-proj (256 blocks, EPI2)
__global__ __launch_bounds__(256)
void gemm_qkv(const short* __restrict__ X, const short* __restrict__ Wq,
              const short* __restrict__ Wkv, const int* __restrict__ sidx,
              short* __restrict__ qb, short* __restrict__ kb,
              short* __restrict__ vt, const int* __restrict__ positions,
              const float* __restrict__ qnw, const float* __restrict__ knw)
{
    __shared__ __align__(16) short As0[64 * 32], Bs0[128 * 32];
    __shared__ __align__(16) short As1[64 * 32], Bs1[128 * 32];
    __shared__ int ridx[64];
    int b = blockIdx.x;
    if (b < 512)
        gemm_core<1>(X, Wq, sidx, qb, 2048, true, b & 15, b >> 4,
                     positions, qnw, nullptr, As0, Bs0, As1, Bs1, ridx);
    else {
        b -= 512;
        gemm_core<2>(X, Wkv, nullptr, kb, 1024, false, b & 7, b >> 3,
                     positions, knw, vt, As0, Bs0, As1, Bs1, ridx);
    }
}

__global__ __launch_bounds__(256)
void gemm_o(const short* __restrict__ X, const short* __restrict__ Wt,
            const int* __restrict__ sidx, float* __restrict__ OUT)
{
    __shared__ __align__(16) short As0[64 * 32], Bs0[128 * 32];
    __shared__ __align__(16) short As1[64 * 32], Bs1[128 * 32];
    __shared__ int ridx[64];
    gemm_core<0>(X, Wt, sidx, OUT, 2048, true, blockIdx.x, blockIdx.y,
                 nullptr, nullptr, nullptr, As0, Bs0, As1, Bs1, ridx);
}

// ---------------------------------------------------------------------------
// D3: blocks [0,512) MFMA flash attention (R3 structure, 16 rows/wave)
// | [512,4608) wtrans o_proj_w into Wo (free overlap: attn doesn't touch Wo).
// R14: NO K/V LDS STAGING. The staged-fragment reads were a pure copy of the
// global layouts (kb[tok][kvh*64+d] and vt[d][token] are exactly the MFMA
// B-fragment layouts), and K/V per kv-head is 256 KB -> L2-resident, shared
// by 64 blocks (Common-mistake #7 / m169: don't LDS-stage L2-fitting data).
// K/V fragments are read directly from global; both per-tile __syncthreads
// and all staging disappear -> the k-loop is barrier-free and the block's 4
// waves drift independently (latency hidden by wave overlap, not lockstep).
// Ps (P round-trip for the PV A-operand) stays in wave-private LDS with
// lgkmcnt-only ordering. s_setprio(1) wraps MFMA clusters (T5).
// ---------------------------------------------------------------------------
__global__ __launch_bounds__(256)
void attn_plus(const short* __restrict__ qb, const short* __restrict__ kb,
               const short* __restrict__ vt, const int* __restrict__ positions,
               short* __restrict__ ob,
               const float* __restrict__ ow, short* __restrict__ Wo)
{
    __shared__ __align__(16) char smem[16896];
    const int b = blockIdx.x;
    const int t = threadIdx.x;

    if (b >= 512) {   // o-weight transpose (T[64][65] floats = 16640 B)
        float (*T)[65] = (float(*)[65])smem;
        int b2 = b - 512;
        int k0 = (b2 & 31) * 64, n0 = ((b2 >> 5) & 31) * 64, e = b2 >> 10;
        wtrans_tile(ow + (size_t)e * 2048 * 2048, Wo + (size_t)e * 2048 * 2048,
                    2048, k0, n0, T, t);
        return;
    }

    short (*Ps)[72] = (short(*)[72])smem;   // [4*16][72] = 9216 B, wave-sliced

    const int head = b >> 4;
    const int kvh  = head >> 2;
    const int lane = t & 63;
    const int wave = t >> 6;
    const int rowg = lane >> 4;
    const int col  = lane & 15;

    const float BIAS = 9.0f * 1.44269504f;

    const short* kbase = kb + kvh * HD;                       // + tok*512 + d
    const short* vbase = vt + (size_t)kvh * HD * N_TOK;       // + d*2048 + tok

#pragma unroll
    for (int pass = 0; pass < 2; pass++) {
        const int qt = pass == 0 ? (31 - (b & 15)) : (b & 15);
        const int q0 = qt * 64;
        const int m0 = q0 + wave * 16;

        const short* qrow = qb + (size_t)(m0 + col) * HID + head * HD;
        short8 aq0 = *(const short8*)(qrow + rowg * 8);
        short8 aq1 = *(const short8*)(qrow + 32 + rowg * 8);

        int pq[4];
        float l_i[4];
#pragma unroll
        for (int r = 0; r < 4; r++) {
            pq[r] = positions[m0 + rowg * 4 + r];
            l_i[r] = 0.f;
        }
        float4v oacc[4];
#pragma unroll
        for (int n = 0; n < 4; n++) oacc[n] = (float4v){0.f, 0.f, 0.f, 0.f};

        const int nkt = qt + 1;

#pragma unroll 1
        for (int kt = 0; kt < nkt; kt++) {
            const int k0 = kt * 64;

            // QK^T: K fragments direct from global (L2-hit)
            float4v c[4];
            __builtin_amdgcn_s_setprio(1);
#pragma unroll
            for (int j = 0; j < 4; j++) {
                const short* kr = kbase + (size_t)(k0 + j * 16 + col) * 512;
                short8 blo = *(const short8*)(kr + rowg * 8);
                short8 bhi = *(const short8*)(kr + 32 + rowg * 8);
                float4v cc = (float4v){0.f, 0.f, 0.f, 0.f};
                cc = __builtin_amdgcn_mfma_f32_16x16x32_bf16(aq0, blo, cc, 0, 0, 0);
                cc = __builtin_amdgcn_mfma_f32_16x16x32_bf16(aq1, bhi, cc, 0, 0, 0);
                c[j] = cc;
            }
            __builtin_amdgcn_s_setprio(0);

            if (kt == qt) {               // diagonal tile masks
#pragma unroll
                for (int j = 0; j < 4; j++) {
                    int pk = positions[k0 + j * 16 + col];
#pragma unroll
                    for (int r = 0; r < 4; r++)
                        if (pq[r] < pk) c[j][r] = -1e30f;
                }
            }

#pragma unroll
            for (int j = 0; j < 4; j++)
#pragma unroll
                for (int r = 0; r < 4; r++) {
                    float p = fast_exp2(c[j][r] - BIAS);
                    l_i[r] += p;
                    Ps[wave * 16 + rowg * 4 + r][j * 16 + col] = f2bf(p);
                }

            __asm__ volatile("s_waitcnt lgkmcnt(0)" ::: "memory");  // Ps wave-private

            short8 ap0 = *(const short8*)&Ps[wave * 16 + col][rowg * 8];
            short8 ap1 = *(const short8*)&Ps[wave * 16 + col][32 + rowg * 8];

            // PV: V fragments direct from global (vt[d][token], token-contig)
            __builtin_amdgcn_s_setprio(1);
#pragma unroll
            for (int n = 0; n < 4; n++) {
                const short* vr = vbase + (size_t)(n * 16 + col) * N_TOK + k0;
                short8 blo = *(const short8*)(vr + rowg * 8);
                short8 bhi = *(const short8*)(vr + 32 + rowg * 8);
                float4v a2 = oacc[n];
                a2 = __builtin_amdgcn_mfma_f32_16x16x32_bf16(ap0, blo, a2, 0, 0, 0);
                a2 = __builtin_amdgcn_mfma_f32_16x16x32_bf16(ap1, bhi, a2, 0, 0, 0);
                oacc[n] = a2;
            }
            __builtin_amdgcn_s_setprio(0);
        }

#pragma unroll
        for (int r = 0; r < 4; r++) {
#pragma unroll
            for (int off = 1; off < 16; off <<= 1)
                l_i[r] += __shfl_xor(l_i[r], off, 64);
            l_i[r] = 1.f / l_i[r];
        }
#pragma unroll
        for (int n = 0; n < 4; n++)
#pragma unroll
            for (int r = 0; r < 4; r++)
                ob[(size_t)(m0 + rowg * 4 + r) * HID + head * HD + n * 16 + col] =
                    f2bf(oacc[n][r] * l_i[r]);
    }
}

// ---------------------------------------------------------------------------
extern "C" void kernel_launch(void* const* d_in, const int* in_sizes, int n_in,
                              void* d_out, int out_size, void* d_ws, size_t ws_size,
                              hipStream_t stream)
{
    (void)in_sizes; (void)n_in; (void)out_size; (void)ws_size;

    const float* hidden    = (const float*)d_in[0];
    const int*   positions = (const int*)  d_in[1];
    const int*   sort_idx  = (const int*)  d_in[2];
    const float* q_proj_w  = (const float*)d_in[3];
    const float* o_proj_w  = (const float*)d_in[4];
    const float* k_w       = (const float*)d_in[5];
    const float* v_w       = (const float*)d_in[6];
    const float* q_norm_w  = (const float*)d_in[7];
    const float* k_norm_w  = (const float*)d_in[8];
    float* out = (float*)d_out;

    const size_t M1 = 1024 * 1024;
    short* Wqo = (short*)d_ws;           // 32 MB: q weights, then o weights
    short* Wkv = Wqo + 16 * M1;          // 4 MB
    short* Xbf = Wkv + 2 * M1;           // 8 MB (aliased as obf later)
    short* qb  = Xbf + 4 * M1;           // 8 MB
    short* kb  = qb  + 4 * M1;           // 2 MB (k only, stride 512)
    short* vt  = kb  + 1 * M1;           // 2 MB (v transposed [d][token])
    short* obf = Xbf;

    prep1<<<6656, 256, 0, stream>>>(hidden, q_proj_w, k_w, v_w, Xbf, Wqo, Wkv);

    gemm_qkv<<<768, 256, 0, stream>>>(Xbf, Wqo, Wkv, sort_idx, qb, kb, vt,
                                      positions, q_norm_w, k_norm_w);

    attn_plus<<<4608, 256, 0, stream>>>(qb, kb, vt, positions, obf,
                                        o_proj_w, Wqo);

    gemm_o<<<dim3(16, 32), 256, 0, stream>>>(obf, Wqo, sort_idx, out);
}

// Round 7
// 270.142 us; speedup vs baseline: 1.4624x; 1.4624x over previous
//
#include <hip/hip_runtime.h>
#include <hip/hip_bf16.h>

#define N_TOK 2048
#define HID   2048
#define NH    32
#define NKV   8
#define HD    64
#define NEXP  4
#define CHUNK (N_TOK / NEXP)   // 512

typedef __attribute__((ext_vector_type(8))) short short8;
typedef __attribute__((ext_vector_type(4))) short short4v;
typedef __attribute__((ext_vector_type(4))) float float4v;

#define QSCALE (0.125f * 1.44269504f)   // softmax scale * log2e (exp2 domain)
#define RLOG   0.41524101186f           // log2(1e4)/32

__device__ inline short f2bf(float f) {
    __hip_bfloat16 h = __float2bfloat16(f);
    return *reinterpret_cast<short*>(&h);
}
__device__ inline float bf2f(short s) {
    __hip_bfloat16 h = *reinterpret_cast<__hip_bfloat16*>(&s);
    return __bfloat162float(h);
}
__device__ __forceinline__ float fast_exp2(float x) {
    float r;
    asm("v_exp_f32 %0, %1" : "=v"(r) : "v"(x));
    return r;
}

// async global->LDS, 16 B per lane; wave-uniform LDS base (m104 caveat).
__device__ __forceinline__ void gld_lds16(const void* g, void* l) {
    __builtin_amdgcn_global_load_lds(
        (const __attribute__((address_space(1))) unsigned int*)g,
        (__attribute__((address_space(3))) unsigned int*)l, 16, 0, 0);
}

// ---------------------------------------------------------------------------
// wtrans tile body: fp32 [k0+64)x[n0+64) of in (row stride Nw) -> bf16
// out[n][2048] transposed; float4-vectorized load, short8-vectorized store.
// ---------------------------------------------------------------------------
__device__ __forceinline__ void wtrans_tile(
    const float* __restrict__ in, short* __restrict__ out, int Nw,
    int k0, int n0, float (*T)[65], int t)
{
    const int nl4 = (t & 15) * 4;
    const int kl  = t >> 4;
#pragma unroll
    for (int i = 0; i < 4; i++) {
        float4 v = *(const float4*)&in[(size_t)(k0 + kl + i * 16) * Nw + n0 + nl4];
        float* Tr = &T[kl + i * 16][nl4];
        Tr[0] = v.x; Tr[1] = v.y; Tr[2] = v.z; Tr[3] = v.w;
    }
    __syncthreads();
#pragma unroll
    for (int i = 0; i < 2; i++) {
        int idx = t + i * 256;
        int nl = idx >> 3, k8 = (idx & 7) * 8;
        short8 s;
#pragma unroll
        for (int j = 0; j < 8; j++) s[j] = f2bf(T[k8 + j][nl]);
        *(short8*)&out[(size_t)(n0 + nl) * 2048 + k0 + k8] = s;
    }
}

// ---------------------------------------------------------------------------
// prep1: [0,2048) cvt hidden->bf16 | [2048,6144) wtrans q_proj_w |
//        [6144,6656) wtrans k_w/v_w.
// ---------------------------------------------------------------------------
__global__ __launch_bounds__(256)
void prep1(const float* __restrict__ hidden, const float* __restrict__ qw,
           const float* __restrict__ kw, const float* __restrict__ vw,
           short* __restrict__ Xbf, short* __restrict__ Wq,
           short* __restrict__ Wkv)
{
    __shared__ float T[64][65];
    const int b = blockIdx.x;
    const int t = threadIdx.x;

    if (b < 2048) {
        size_t i = (size_t)b * 256 + t;
        float4 a = ((const float4*)hidden)[i * 2];
        float4 c = ((const float4*)hidden)[i * 2 + 1];
        short8 s;
        s[0] = f2bf(a.x); s[1] = f2bf(a.y); s[2] = f2bf(a.z); s[3] = f2bf(a.w);
        s[4] = f2bf(c.x); s[5] = f2bf(c.y); s[6] = f2bf(c.z); s[7] = f2bf(c.w);
        ((short8*)Xbf)[i] = s;
    } else if (b < 6144) {
        int b2 = b - 2048;
        int k0 = (b2 & 31) * 64, n0 = ((b2 >> 5) & 31) * 64, e = b2 >> 10;
        wtrans_tile(qw + (size_t)e * 2048 * 2048, Wq + (size_t)e * 2048 * 2048,
                    2048, k0, n0, T, t);
    } else {
        int b3 = b - 6144;
        int k0 = (b3 & 31) * 64, n0 = ((b3 >> 5) & 7) * 64, z = b3 >> 8;
        wtrans_tile(z ? vw : kw, Wkv + (size_t)z * 512 * 2048, 512, k0, n0, T, t);
    }
}

// ---------------------------------------------------------------------------
// bf16 MFMA GEMM core, 64x128 tile (M x N), BK=64, 4 waves (wave = 32x64).
// R15: PHASE-COUNT round. R0/R2/R3 all pinned at 55-65us with exactly 64
// K-phases (BK=32) across occupancies 1-3 blk/CU and pipeline depths 0-3
// -> per-phase fixed cost ~870ns dominates; the untested axis is phase
// count. BK=64 halves phases to 32 (2x MFMA + 2x staged bytes per phase,
// half the barrier/vmcnt events). LDS 48KB (2 x [64][64]A + [128][64]B),
// still 3 blk/CU.
// Swizzle (both-sides involution, m104-safe): write side stays LDS-linear,
// global source granule g = s ^ (row&7) via per-lane seg = ((l&7)^(l>>3))*8
// (row&7 == l>>3 for every staging instr since all row bases are 0 mod 8);
// read side slot = (kk*4+rowg) ^ (col&7) (row&7 == col&7 for fragment rows).
// 16-lane read group covers 8 distinct 16B slots x2 -> 2 lanes/bank (free).
// Fused epilogues unchanged (wave N-tile 64 cols == one head):
//   EPI 0: fp32 store (o-proj)
//   EPI 1: q RMSNorm + RoPE + QSCALE, bf16 store to qb (stride 2048)
//   EPI 2: kv GEMM -- k cols (n<512): RMSNorm+RoPE -> kb (stride 512);
//          v cols: transposed bf16 store to vt[d][token] (stride 2048)
// ---------------------------------------------------------------------------
template <int EPI>
__device__ __forceinline__ void gemm_core(
    const short* __restrict__ X, const short* __restrict__ Wt,
    const int* __restrict__ sidx, void* __restrict__ OUT,
    int dout, bool routed, int bx, int by,
    const int* __restrict__ positions, const float* __restrict__ nw,
    short* __restrict__ vt,
    short* As0, short* Bs0, short* As1, short* Bs1, int* ridx)
{
    const int t  = threadIdx.x;
    const int m0 = by * 64;
    const int n0 = bx * 128;

    if (t < 64) ridx[t] = routed ? sidx[m0 + t] : (m0 + t);
    __syncthreads();

    const short* Wb = Wt + (routed ? (size_t)(m0 / CHUNK) * (size_t)dout * 2048 : 0);

    const int lane = t & 63;
    const int wave = t >> 6;
    const int lr   = lane >> 3;                 // sub-row within staging instr
    const int seg  = ((lane & 7) ^ lr) * 8;     // swizzled k-granule (shorts)

    // staging sources: A rows wave*16 + {0,8} + lr (ridx-gathered);
    //                  B rows n0 + wave*32 + {0,8,16,24} + lr (contiguous)
    const short* ga0 = X + (size_t)ridx[wave * 16 + lr] * 2048 + seg;
    const short* ga1 = X + (size_t)ridx[wave * 16 + 8 + lr] * 2048 + seg;
    const short* gb  = Wb + (size_t)(n0 + wave * 32 + lr) * 2048 + seg;

    const int col  = lane & 15;
    const int rowg = lane >> 4;
    const int wm   = (wave >> 1) * 32;   // M-half of the 64-row tile
    const int wn   = (wave & 1) * 64;    // N-half (one head)

    float4v acc[2][4];
#pragma unroll
    for (int mt = 0; mt < 2; mt++)
#pragma unroll
        for (int nt = 0; nt < 4; nt++) acc[mt][nt] = (float4v){0.f, 0.f, 0.f, 0.f};

    auto stage = [&](int k0, short* A, short* B) {
        gld_lds16(ga0 + k0, A + wave * 1024);
        gld_lds16(ga1 + k0, A + wave * 1024 + 512);
        gld_lds16(gb + k0,             B + wave * 2048);
        gld_lds16(gb + 8 * 2048 + k0,  B + wave * 2048 + 512);
        gld_lds16(gb + 16 * 2048 + k0, B + wave * 2048 + 1024);
        gld_lds16(gb + 24 * 2048 + k0, B + wave * 2048 + 1536);
    };
    auto compute = [&](const short* A, const short* B) {
#pragma unroll
        for (int kk = 0; kk < 2; kk++) {
            const int sl = (((kk * 4 + rowg) ^ (col & 7))) * 8;
            short8 af[2], bfr[4];
#pragma unroll
            for (int i = 0; i < 2; i++)
                af[i] = *(const short8*)&A[(wm + i * 16 + col) * 64 + sl];
#pragma unroll
            for (int i = 0; i < 4; i++)
                bfr[i] = *(const short8*)&B[(wn + i * 16 + col) * 64 + sl];
#pragma unroll
            for (int mt = 0; mt < 2; mt++)
#pragma unroll
                for (int nt = 0; nt < 4; nt++)
                    acc[mt][nt] = __builtin_amdgcn_mfma_f32_16x16x32_bf16(
                        af[mt], bfr[nt], acc[mt][nt], 0, 0, 0);
        }
    };

    stage(0, As0, Bs0);
    asm volatile("s_waitcnt vmcnt(0)" ::: "memory");
    __builtin_amdgcn_s_barrier();

#pragma unroll 1
    for (int k0 = 0; k0 < 2048; k0 += 128) {
        if (k0 + 64 < 2048) stage(k0 + 64, As1, Bs1);
        compute(As0, Bs0);
        asm volatile("s_waitcnt vmcnt(0)" ::: "memory");
        __builtin_amdgcn_s_barrier();

        if (k0 + 128 < 2048) stage(k0 + 128, As0, Bs0);
        compute(As1, Bs1);
        asm volatile("s_waitcnt vmcnt(0)" ::: "memory");
        __builtin_amdgcn_s_barrier();
    }

    if (EPI == 0) {
#pragma unroll
        for (int mt = 0; mt < 2; mt++)
#pragma unroll
            for (int r = 0; r < 4; r++) {
                int row = ridx[wm + mt * 16 + rowg * 4 + r];
#pragma unroll
                for (int nt = 0; nt < 4; nt++)
                    ((float*)OUT)[(size_t)row * dout + n0 + wn + nt * 16 + col] =
                        acc[mt][nt][r];
            }
        return;
    }

    const bool is_v = (EPI == 2) && (n0 + wn >= 512);

    if (is_v) {   // transposed bf16 store: vt[d][token], 4 tokens per store
#pragma unroll
        for (int mt = 0; mt < 2; mt++) {
            int rowb = m0 + wm + mt * 16 + rowg * 4;   // identity rows (kv)
#pragma unroll
            for (int nt = 0; nt < 4; nt++) {
                int d = n0 + wn + nt * 16 + col - 512;
                short4v sv;
#pragma unroll
                for (int r = 0; r < 4; r++) sv[r] = f2bf(acc[mt][nt][r]);
                *(short4v*)&vt[(size_t)d * N_TOK + rowb] = sv;
            }
        }
        return;
    }

    // q (EPI 1) or k (EPI 2, n<512): RMSNorm + NeoX RoPE, bf16 store
    {
        const int   h     = (n0 + wn) >> 6;
        const float oscl  = (EPI == 1) ? QSCALE : 1.0f;
        const int   ldo   = (EPI == 1) ? 2048 : 512;
        short* ob = (short*)OUT;
        float invf0 = fast_exp2(-(float)col * RLOG);          // j = col
        float invf1 = fast_exp2(-(float)(16 + col) * RLOG);   // j = 16+col
        float wv[4];
#pragma unroll
        for (int nt = 0; nt < 4; nt++) wv[nt] = nw[nt * 16 + col];

#pragma unroll
        for (int mt = 0; mt < 2; mt++)
#pragma unroll
            for (int r = 0; r < 4; r++) {
                int row = ridx[wm + mt * 16 + rowg * 4 + r];
                float x0 = acc[mt][0][r], x1 = acc[mt][1][r];
                float x2 = acc[mt][2][r], x3 = acc[mt][3][r];
                float ss = x0 * x0 + x1 * x1 + x2 * x2 + x3 * x3;
#pragma unroll
                for (int off = 1; off < 16; off <<= 1)
                    ss += __shfl_xor(ss, off, 64);
                float rs = rsqrtf(ss * (1.0f / HD) + 1e-6f);
                x0 *= rs * wv[0]; x1 *= rs * wv[1];
                x2 *= rs * wv[2]; x3 *= rs * wv[3];
                float pos = (float)positions[row];
                float fr0 = pos * invf0, fr1 = pos * invf1;
                float c0 = __cosf(fr0), s0 = __sinf(fr0);
                float c1 = __cosf(fr1), s1 = __sinf(fr1);
                float o0 = x0 * c0 - x2 * s0;
                float o1 = x1 * c1 - x3 * s1;
                float o2 = x2 * c0 + x0 * s0;
                float o3 = x3 * c1 + x1 * s1;
                size_t base = (size_t)row * ldo + h * 64 + col;
                ob[base]      = f2bf(o0 * oscl);
                ob[base + 16] = f2bf(o1 * oscl);
                ob[base + 32] = f2bf(o2 * oscl);
                ob[base + 48] = f2bf(o3 * oscl);
            }
    }
}

// fused q-proj (512 blocks, routed, EPI1) + kv-proj (256 blocks, EPI2)
__global__ __launch_bounds__(256)
void gemm_qkv(const short* __restrict__ X, const short* __restrict__ Wq,
              const short* __restrict__ Wkv, const int* __restrict__ sidx,
              short* __restrict__ qb, short* __restrict__ kb,
              short* __restrict__ vt, const int* __restrict__ positions,
              const float* __restrict__ qnw, const float* __restrict__ knw)
{
    __shared__ __align__(16) short As0[64 * 64], Bs0[128 * 64];
    __shared__ __align__(16) short As1[64 * 64], Bs1[128 * 64];
    __shared__ int ridx[64];
    int b = blockIdx.x;
    if (b < 512)
        gemm_core<1>(X, Wq, sidx, qb, 2048, true, b & 15, b >> 4,
                     positions, qnw, nullptr, As0, Bs0, As1, Bs1, ridx);
    else {
        b -= 512;
        gemm_core<2>(X, Wkv, nullptr, kb, 1024, false, b & 7, b >> 3,
                     positions, knw, vt, As0, Bs0, As1, Bs1, ridx);
    }
}

__global__ __launch_bounds__(256)
void gemm_o(const short* __restrict__ X, const short* __restrict__ Wt,
            const int* __restrict__ sidx, float* __restrict__ OUT)
{
    __shared__ __align__(16) short As0[64 * 64], Bs0[128 * 64];
    __shared__ __align__(16) short As1[64 * 64], Bs1[128 * 64];
    __shared__ int ridx[64];
    gemm_core<0>(X, Wt, sidx, OUT, 2048, true, blockIdx.x, blockIdx.y,
                 nullptr, nullptr, nullptr, As0, Bs0, As1, Bs1, ridx);
}

// ---------------------------------------------------------------------------
// D3: blocks [0,512) MFMA flash attention (R3-proven structure: 16 rows/wave,
// K/V LDS staging + register next-tile prefetch — the staging IS the
// coalescer; R6's direct-global fragment reads were 16-way scattered and
// 2.5x slower) | [512,4608) wtrans o_proj_w into Wo (free overlap).
// Only addition vs R3: s_setprio(1) around the MFMA clusters (T5).
// ---------------------------------------------------------------------------
__global__ __launch_bounds__(256)
void attn_plus(const short* __restrict__ qb, const short* __restrict__ kb,
               const short* __restrict__ vt, const int* __restrict__ positions,
               short* __restrict__ ob,
               const float* __restrict__ ow, short* __restrict__ Wo)
{
    __shared__ __align__(16) char smem[27648];
    const int b = blockIdx.x;
    const int t = threadIdx.x;

    if (b >= 512) {   // o-weight transpose
        float (*T)[65] = (float(*)[65])smem;
        int b2 = b - 512;
        int k0 = (b2 & 31) * 64, n0 = ((b2 >> 5) & 31) * 64, e = b2 >> 10;
        wtrans_tile(ow + (size_t)e * 2048 * 2048, Wo + (size_t)e * 2048 * 2048,
                    2048, k0, n0, T, t);
        return;
    }

    short (*Ks)[72] = (short(*)[72])smem;                      // 64x72
    short (*Vt)[72] = (short(*)[72])(smem + 64 * 72 * 2);      // 64x72
    short (*Ps)[72] = (short(*)[72])(smem + 2 * 64 * 72 * 2);  // [4*16][72]

    const int head = b >> 4;
    const int kvh  = head >> 2;
    const int lane = t & 63;
    const int wave = t >> 6;
    const int rowg = lane >> 4;
    const int col  = lane & 15;

    const int sr = t >> 2;
    const int sc = (t & 3) * 16;
    const float BIAS = 9.0f * 1.44269504f;

#pragma unroll
    for (int pass = 0; pass < 2; pass++) {
        const int qt = pass == 0 ? (31 - (b & 15)) : (b & 15);
        const int q0 = qt * 64;
        const int m0 = q0 + wave * 16;

        const short* qrow = qb + (size_t)(m0 + col) * HID + head * HD;
        short8 aq0 = *(const short8*)(qrow + rowg * 8);
        short8 aq1 = *(const short8*)(qrow + 32 + rowg * 8);

        int pq[4];
        float l_i[4];
#pragma unroll
        for (int r = 0; r < 4; r++) {
            pq[r] = positions[m0 + rowg * 4 + r];
            l_i[r] = 0.f;
        }
        float4v oacc[4];
#pragma unroll
        for (int n = 0; n < 4; n++) oacc[n] = (float4v){0.f, 0.f, 0.f, 0.f};

        const short* kpb = kb + (size_t)sr * 512 + kvh * HD + sc;
        const short* vpb = vt + ((size_t)kvh * HD + sr) * N_TOK + sc;

        const int nkt = qt + 1;
        short8 kA, kB, vA, vB;
        {   // preload tile 0
            kA = *(const short8*)(kpb);
            kB = *(const short8*)(kpb + 8);
            vA = *(const short8*)(vpb);
            vB = *(const short8*)(vpb + 8);
        }

        for (int kt = 0; kt < nkt; kt++) {
            __syncthreads();              // prev tile's LDS reads done
            *(short8*)&Ks[sr][sc]     = kA;
            *(short8*)&Ks[sr][sc + 8] = kB;
            *(short8*)&Vt[sr][sc]     = vA;
            *(short8*)&Vt[sr][sc + 8] = vB;
            __syncthreads();              // tile staged

            if (kt + 1 < nkt) {           // prefetch next tile (latency hidden)
                kA = *(const short8*)(kpb + (size_t)(kt + 1) * 64 * 512);
                kB = *(const short8*)(kpb + (size_t)(kt + 1) * 64 * 512 + 8);
                vA = *(const short8*)(vpb + (kt + 1) * 64);
                vB = *(const short8*)(vpb + (kt + 1) * 64 + 8);
            }

            const int k0 = kt * 64;
            float4v c[4];
            __builtin_amdgcn_s_setprio(1);
#pragma unroll
            for (int j = 0; j < 4; j++) {
                short8 blo = *(const short8*)&Ks[j * 16 + col][rowg * 8];
                short8 bhi = *(const short8*)&Ks[j * 16 + col][32 + rowg * 8];
                float4v cc = (float4v){0.f, 0.f, 0.f, 0.f};
                cc = __builtin_amdgcn_mfma_f32_16x16x32_bf16(aq0, blo, cc, 0, 0, 0);
                cc = __builtin_amdgcn_mfma_f32_16x16x32_bf16(aq1, bhi, cc, 0, 0, 0);
                c[j] = cc;
            }
            __builtin_amdgcn_s_setprio(0);

            if (kt == qt) {               // diagonal tile masks
#pragma unroll
                for (int j = 0; j < 4; j++) {
                    int pk = positions[k0 + j * 16 + col];
#pragma unroll
                    for (int r = 0; r < 4; r++)
                        if (pq[r] < pk) c[j][r] = -1e30f;
                }
            }

#pragma unroll
            for (int j = 0; j < 4; j++)
#pragma unroll
                for (int r = 0; r < 4; r++) {
                    float p = fast_exp2(c[j][r] - BIAS);
                    l_i[r] += p;
                    Ps[wave * 16 + rowg * 4 + r][j * 16 + col] = f2bf(p);
                }

            __asm__ volatile("s_waitcnt lgkmcnt(0)" ::: "memory");  // Ps wave-private

            short8 ap0 = *(const short8*)&Ps[wave * 16 + col][rowg * 8];
            short8 ap1 = *(const short8*)&Ps[wave * 16 + col][32 + rowg * 8];
            __builtin_amdgcn_s_setprio(1);
#pragma unroll
            for (int n = 0; n < 4; n++) {
                short8 blo = *(const short8*)&Vt[n * 16 + col][rowg * 8];
                short8 bhi = *(const short8*)&Vt[n * 16 + col][32 + rowg * 8];
                float4v a2 = oacc[n];
                a2 = __builtin_amdgcn_mfma_f32_16x16x32_bf16(ap0, blo, a2, 0, 0, 0);
                a2 = __builtin_amdgcn_mfma_f32_16x16x32_bf16(ap1, bhi, a2, 0, 0, 0);
                oacc[n] = a2;
            }
            __builtin_amdgcn_s_setprio(0);
        }

#pragma unroll
        for (int r = 0; r < 4; r++) {
#pragma unroll
            for (int off = 1; off < 16; off <<= 1)
                l_i[r] += __shfl_xor(l_i[r], off, 64);
            l_i[r] = 1.f / l_i[r];
        }
#pragma unroll
        for (int n = 0; n < 4; n++)
#pragma unroll
            for (int r = 0; r < 4; r++)
                ob[(size_t)(m0 + rowg * 4 + r) * HID + head * HD + n * 16 + col] =
                    f2bf(oacc[n][r] * l_i[r]);
    }
}

// ---------------------------------------------------------------------------
extern "C" void kernel_launch(void* const* d_in, const int* in_sizes, int n_in,
                              void* d_out, int out_size, void* d_ws, size_t ws_size,
                              hipStream_t stream)
{
    (void)in_sizes; (void)n_in; (void)out_size; (void)ws_size;

    const float* hidden    = (const float*)d_in[0];
    const int*   positions = (const int*)  d_in[1];
    const int*   sort_idx  = (const int*)  d_in[2];
    const float* q_proj_w  = (const float*)d_in[3];
    const float* o_proj_w  = (const float*)d_in[4];
    const float* k_w       = (const float*)d_in[5];
    const float* v_w       = (const float*)d_in[6];
    const float* q_norm_w  = (const float*)d_in[7];
    const float* k_norm_w  = (const float*)d_in[8];
    float* out = (float*)d_out;

    const size_t M1 = 1024 * 1024;
    short* Wqo = (short*)d_ws;           // 32 MB: q weights, then o weights
    short* Wkv = Wqo + 16 * M1;          // 4 MB
    short* Xbf = Wkv + 2 * M1;           // 8 MB (aliased as obf later)
    short* qb  = Xbf + 4 * M1;           // 8 MB
    short* kb  = qb  + 4 * M1;           // 2 MB (k only, stride 512)
    short* vt  = kb  + 1 * M1;           // 2 MB (v transposed [d][token])
    short* obf = Xbf;

    prep1<<<6656, 256, 0, stream>>>(hidden, q_proj_w, k_w, v_w, Xbf, Wqo, Wkv);

    gemm_qkv<<<768, 256, 0, stream>>>(Xbf, Wqo, Wkv, sort_idx, qb, kb, vt,
                                      positions, q_norm_w, k_norm_w);

    attn_plus<<<4608, 256, 0, stream>>>(qb, kb, vt, positions, obf,
                                        o_proj_w, Wqo);

    gemm_o<<<dim3(16, 32), 256, 0, stream>>>(obf, Wqo, sort_idx, out);
}